// Round 11
// baseline (324.063 us; speedup 1.0000x reference)
//
#include <hip/hip_runtime.h>
#include <math.h>

typedef unsigned short u16;
typedef __attribute__((ext_vector_type(8))) short short8;
typedef __attribute__((ext_vector_type(4))) float floatx4;
typedef __attribute__((ext_vector_type(4))) short sh4v;

union sh4u { sh4v v; u16 u[4]; };
union sh8u { short8 v; u16 u[8]; };

__device__ __forceinline__ floatx4 mfma16(short8 a, short8 b, floatx4 c) {
  return __builtin_amdgcn_mfma_f32_16x16x32_bf16(a, b, c, 0, 0, 0);
}

__device__ __forceinline__ floatx4 zero4() {
  floatx4 z = {0.f, 0.f, 0.f, 0.f};
  return z;
}

__device__ __forceinline__ u16 f2b(float f) {
  union { float f; unsigned u; } v; v.f = f;
  unsigned u = v.u;
  return (u16)((u + 0x7FFFu + ((u >> 16) & 1u)) >> 16);
}

__device__ __forceinline__ float b2f(u16 u) {
  union { unsigned u; float f; } v; v.u = ((unsigned)u) << 16;
  return v.f;
}

__device__ __forceinline__ float gelu_exact(float x) {
  return 0.5f * x * (1.f + erff(x * 0.70710678118654752440f));
}

__device__ __forceinline__ unsigned pack2(float a, float b) {
  return (unsigned)f2b(a) | ((unsigned)f2b(b) << 16);
}

// truncating pack of two f32 -> two bf16 in one v_perm
__device__ __forceinline__ unsigned permpack(float p0, float p1) {
  return __builtin_amdgcn_perm(__float_as_uint(p1), __float_as_uint(p0), 0x07060302u);
}

// ------------- fat kernel: weight transpose-convert (blocks 0..611) + LN1 (612..2659) -------------
__global__ __launch_bounds__(256) void tcln_kernel(
    const float* __restrict__ p0, const float* __restrict__ p1,
    const float* __restrict__ p2, const float* __restrict__ p3,
    const float* __restrict__ p4, const float* __restrict__ p5,
    const float* __restrict__ wknn,
    u16* __restrict__ o0, u16* __restrict__ o1, u16* __restrict__ o2,
    u16* __restrict__ o3, u16* __restrict__ o4, u16* __restrict__ o5,
    u16* __restrict__ wcT,
    const float* __restrict__ x, const float* __restrict__ g,
    const float* __restrict__ bia, u16* __restrict__ nx) {
  __shared__ u16 L[64][66];
  int t = blockIdx.x, tid = threadIdx.x;
  if (t >= 612) {
    // ---- LN1: one wave per row ----
    int wave = tid >> 6, lane = tid & 63;
    int row = (t - 612) * 4 + wave;
    const float* xr = x + (size_t)row * 384;
    float v[6];
    float s = 0.f;
#pragma unroll
    for (int j = 0; j < 6; j++) { v[j] = xr[lane + 64 * j]; s += v[j]; }
#pragma unroll
    for (int off = 32; off > 0; off >>= 1) s += __shfl_xor(s, off);
    float mu = s * (1.f / 384.f);
    float ss = 0.f;
#pragma unroll
    for (int j = 0; j < 6; j++) { float d = v[j] - mu; ss += d * d; }
#pragma unroll
    for (int off = 32; off > 0; off >>= 1) ss += __shfl_xor(ss, off);
    float rstd = rsqrtf(ss * (1.f / 384.f) + 1e-5f);
    u16* orow = nx + (size_t)row * 384;
#pragma unroll
    for (int j = 0; j < 6; j++) {
      int d = lane + 64 * j;
      orow[d] = f2b((v[j] - mu) * rstd * g[d] + bia[d]);
    }
    return;
  }
  if (t >= 540) {
    t -= 540;                       // wcT: 6 k-tiles x 12 j-tiles
    int tk = t / 12, tn = t % 12;
    int k0 = tk * 64, j0 = tn * 64;
#pragma unroll
    for (int i = 0; i < 4; i++) {
      int c = tid + 256 * i;
      int r = c >> 4, c4 = (c & 15) * 4;
      floatx4 v;
      if (j0 < 384) {
        v = *(const floatx4*)(wknn + (size_t)(k0 + r) * 384 + j0 + c4);
      } else {
        floatx4 a = *(const floatx4*)(wknn + (size_t)(384 + k0 + r) * 384 + (j0 - 384) + c4);
        floatx4 b = *(const floatx4*)(wknn + (size_t)(k0 + r) * 384 + (j0 - 384) + c4);
        v = a - b;
      }
      *(unsigned*)&L[r][c4]     = pack2(v[0], v[1]);
      *(unsigned*)&L[r][c4 + 2] = pack2(v[2], v[3]);
    }
    __syncthreads();
#pragma unroll
    for (int i = 0; i < 2; i++) {
      int c = tid + 256 * i;
      int nn = c >> 3, k8 = (c & 7) * 8;
      sh8u pk;
#pragma unroll
      for (int j = 0; j < 8; j++) pk.u[j] = L[k8 + j][nn];
      *(short8*)(wcT + (size_t)(j0 + nn) * 384 + k0 + k8) = pk.v;
    }
    return;
  }
  const float* src; u16* dst; int Kd, Nd, tk, tn;
  if      (t < 108) { src = p0; dst = o0; Kd = 384;  Nd = 1152; tk = t / 18; tn = t % 18; }
  else if (t < 144) { src = p1; dst = o1; Kd = 384;  Nd = 384;  t -= 108; tk = t / 6;  tn = t % 6; }
  else if (t < 216) { src = p2; dst = o2; Kd = 768;  Nd = 384;  t -= 144; tk = t / 6;  tn = t % 6; }
  else if (t < 252) { src = p3; dst = o3; Kd = 384;  Nd = 384;  t -= 216; tk = t / 6;  tn = t % 6; }
  else if (t < 396) { src = p4; dst = o4; Kd = 384;  Nd = 1536; t -= 252; tk = t / 24; tn = t % 24; }
  else              { src = p5; dst = o5; Kd = 1536; Nd = 384;  t -= 396; tk = t / 6;  tn = t % 6; }
  int k0 = tk * 64, n0 = tn * 64;
#pragma unroll
  for (int i = 0; i < 4; i++) {
    int c = tid + 256 * i;
    int r = c >> 4, c4 = (c & 15) * 4;
    floatx4 v = *(const floatx4*)(src + (size_t)(k0 + r) * Nd + n0 + c4);
    *(unsigned*)&L[r][c4]     = pack2(v[0], v[1]);
    *(unsigned*)&L[r][c4 + 2] = pack2(v[2], v[3]);
  }
  __syncthreads();
#pragma unroll
  for (int i = 0; i < 2; i++) {
    int c = tid + 256 * i;
    int nn = c >> 3, k8 = (c & 7) * 8;
    sh8u pk;
#pragma unroll
    for (int j = 0; j < 8; j++) pk.u[j] = L[k8 + j][nn];
    *(short8*)(dst + (size_t)(n0 + nn) * Kd + k0 + k8) = pk.v;
  }
}

// ---------------- LayerNorm (bf16 in -> bf16 out), one wave per row of 384 ----------------
__global__ __launch_bounds__(256) void lnb_kernel(const u16* __restrict__ x,
                                                  const float* __restrict__ g,
                                                  const float* __restrict__ bia,
                                                  u16* __restrict__ out) {
  int wave = threadIdx.x >> 6, lane = threadIdx.x & 63;
  int row = blockIdx.x * 4 + wave;
  const u16* xr = x + (size_t)row * 384;
  float v[6];
  float s = 0.f;
#pragma unroll
  for (int j = 0; j < 6; j++) { v[j] = b2f(xr[lane + 64 * j]); s += v[j]; }
#pragma unroll
  for (int off = 32; off > 0; off >>= 1) s += __shfl_xor(s, off);
  float mu = s * (1.f / 384.f);
  float ss = 0.f;
#pragma unroll
  for (int j = 0; j < 6; j++) { float d = v[j] - mu; ss += d * d; }
#pragma unroll
  for (int off = 32; off > 0; off >>= 1) ss += __shfl_xor(ss, off);
  float rstd = rsqrtf(ss * (1.f / 384.f) + 1e-5f);
  u16* orow = out + (size_t)row * 384;
#pragma unroll
  for (int j = 0; j < 6; j++) {
    int d = lane + 64 * j;
    orow[d] = f2b((v[j] - mu) * rstd * g[d] + bia[d]);
  }
}

// ---------------- gemm128p: 128x128 tile, BK=64, reg-prefetch dbuf ----------------
// EPI: 3 gelu(+bias) -> bf16 | 8 fused qkv+GB (Q pre-scale, V^T scatter / GBb)
template <int EPI>
__global__ __launch_bounds__(256) void gemm128p_kernel(
    const u16* __restrict__ A0, const u16* __restrict__ BwT,
    const u16* __restrict__ BwT2, int N, int K,
    const float* __restrict__ bias, u16* __restrict__ outB, u16* __restrict__ outB2,
    u16* __restrict__ outV) {
  __shared__ u16 As[128][72];
  __shared__ u16 Bs[128][72];
  int tid = threadIdx.x;
  int lane = tid & 63, wave = tid >> 6, quad = lane >> 4, l16 = lane & 15;
  int n0 = blockIdx.x * 128, m0 = blockIdx.y * 128;
  int wm = (wave >> 1) * 64, wn = (wave & 1) * 64;
  int ra = tid >> 3, ca = (tid & 7) * 8;
  const u16* Bsrc = BwT;
  int nbase = n0;
  if (EPI == 8 && n0 >= 1152) { Bsrc = BwT2; nbase = n0 - 1152; }
  floatx4 acc[4][4];
#pragma unroll
  for (int i = 0; i < 4; i++)
#pragma unroll
    for (int j = 0; j < 4; j++) acc[i][j] = zero4();

  short8 pa[4], pb[4];
  auto loadAB = [&](int k0) {
#pragma unroll
    for (int i = 0; i < 4; i++) {
      pa[i] = *(const short8*)(A0 + (size_t)(m0 + ra + 32 * i) * K + k0 + ca);
      pb[i] = *(const short8*)(Bsrc + (size_t)(nbase + ra + 32 * i) * K + k0 + ca);
    }
  };
  loadAB(0);
  int iters = K >> 6;
  for (int kt = 0; kt < iters; kt++) {
    __syncthreads();
#pragma unroll
    for (int i = 0; i < 4; i++) {
      *(short8*)&As[ra + 32 * i][ca] = pa[i];
      *(short8*)&Bs[ra + 32 * i][ca] = pb[i];
    }
    __syncthreads();
    if (kt + 1 < iters) loadAB((kt + 1) * 64);
#pragma unroll
    for (int kh = 0; kh < 2; kh++) {
      short8 af[4], bfr[4];
#pragma unroll
      for (int ti = 0; ti < 4; ti++)
        af[ti] = *(const short8*)&As[wm + ti * 16 + l16][kh * 32 + quad * 8];
#pragma unroll
      for (int tj = 0; tj < 4; tj++)
        bfr[tj] = *(const short8*)&Bs[wn + tj * 16 + l16][kh * 32 + quad * 8];
#pragma unroll
      for (int ti = 0; ti < 4; ti++)
#pragma unroll
        for (int tj = 0; tj < 4; tj++)
          acc[ti][tj] = mfma16(af[ti], bfr[tj], acc[ti][tj]);
    }
  }

#pragma unroll
  for (int ti = 0; ti < 4; ti++)
#pragma unroll
    for (int tj = 0; tj < 4; tj++) {
      int col = n0 + wn + tj * 16 + l16;
      int row0 = m0 + wm + ti * 16 + quad * 4;
      if (EPI == 8) {
        if (col < 1152) {
          float sc = (col < 384) ? 0.18033688011112042f : 1.f;  // Q * 0.125*log2(e)
          sh4u pk;
#pragma unroll
          for (int r = 0; r < 4; r++) {
            u16 bv = f2b(acc[ti][tj][r] * sc);
            outB[(size_t)(row0 + r) * 1152 + col] = bv;
            pk.u[r] = bv;
          }
          if (col >= 768) {
            int b = row0 >> 11, n = row0 & 2047;
            int hd = col - 768;
            *(sh4v*)(outV + ((size_t)(b * 6 + (hd >> 6)) * 64 + (hd & 63)) * 2048 + n) = pk.v;
          }
        } else {
#pragma unroll
          for (int r = 0; r < 4; r++)
            outB2[(size_t)(row0 + r) * 768 + (col - 1152)] = f2b(acc[ti][tj][r]);
        }
      } else {
#pragma unroll
        for (int r = 0; r < 4; r++)
          outB[(size_t)(row0 + r) * N + col] = f2b(gelu_exact(acc[ti][tj][r] + bias[col]));
      }
    }
}

// ---------------- gemm64: 64Mx128N tile, BK=64, reg-prefetch dbuf ----------------
// EPI: 3 gelu(+bias) -> bf16 | 7 +bias + bf16-resid -> f32
template <int EPI>
__global__ __launch_bounds__(256) void gemm64_kernel(
    const u16* __restrict__ A0, const u16* __restrict__ A1, int Ksplit,
    const u16* __restrict__ BwT, int N, int K,
    const float* __restrict__ bias,
    float* __restrict__ outF, u16* __restrict__ outB,
    const u16* __restrict__ eA16) {
  __shared__ u16 As[64][72];
  __shared__ u16 Bs[128][72];
  int tid = threadIdx.x;
  int lane = tid & 63, w = tid >> 6, quad = lane >> 4, l16 = lane & 15;
  int n0 = blockIdx.x * 128, m0 = blockIdx.y * 64;
  int ra = tid >> 3, ca = (tid & 7) * 8;
  floatx4 acc[4][2];
#pragma unroll
  for (int i = 0; i < 4; i++)
#pragma unroll
    for (int j = 0; j < 2; j++) acc[i][j] = zero4();

  short8 pa[2], pb[4];
  auto loadAB = [&](int k0) {
    const u16* Ap;
    int kk, sA;
    if (k0 < Ksplit) { Ap = A0; kk = k0; sA = Ksplit; }
    else             { Ap = A1; kk = k0 - Ksplit; sA = K - Ksplit; }
    pa[0] = *(const short8*)(Ap + (size_t)(m0 + ra) * sA + kk + ca);
    pa[1] = *(const short8*)(Ap + (size_t)(m0 + ra + 32) * sA + kk + ca);
#pragma unroll
    for (int i = 0; i < 4; i++)
      pb[i] = *(const short8*)(BwT + (size_t)(n0 + ra + 32 * i) * K + k0 + ca);
  };
  loadAB(0);
  int iters = K >> 6;
  for (int kt = 0; kt < iters; kt++) {
    __syncthreads();
    *(short8*)&As[ra][ca] = pa[0];
    *(short8*)&As[ra + 32][ca] = pa[1];
#pragma unroll
    for (int i = 0; i < 4; i++) *(short8*)&Bs[ra + 32 * i][ca] = pb[i];
    __syncthreads();
    if (kt + 1 < iters) loadAB((kt + 1) * 64);
#pragma unroll
    for (int kh = 0; kh < 2; kh++) {
      short8 af[4], bfr[2];
#pragma unroll
      for (int mt = 0; mt < 4; mt++)
        af[mt] = *(const short8*)&As[mt * 16 + l16][kh * 32 + quad * 8];
#pragma unroll
      for (int nt = 0; nt < 2; nt++)
        bfr[nt] = *(const short8*)&Bs[w * 32 + nt * 16 + l16][kh * 32 + quad * 8];
#pragma unroll
      for (int mt = 0; mt < 4; mt++)
#pragma unroll
        for (int nt = 0; nt < 2; nt++)
          acc[mt][nt] = mfma16(af[mt], bfr[nt], acc[mt][nt]);
    }
  }

#pragma unroll
  for (int mt = 0; mt < 4; mt++)
#pragma unroll
    for (int nt = 0; nt < 2; nt++) {
      int col = n0 + w * 32 + nt * 16 + l16;
      int row0 = m0 + mt * 16 + quad * 4;
#pragma unroll
      for (int r = 0; r < 4; r++) {
        size_t rc = (size_t)(row0 + r) * N + col;
        float v = acc[mt][nt][r];
        if (EPI == 3) {
          outB[rc] = f2b(gelu_exact(v + bias[col]));
        } else if (EPI == 7) {
          outF[rc] = v + bias[col] + b2f(eA16[rc]);
        }
      }
    }
}

// ---------------- gemm32: 32Mx128N tile, BK=64, reg-prefetch, high-occupancy ----------------
// EPI: 4 gate -> bf16 | 9 proj: 4-split combine in staging, normalize in epilogue
template <int EPI>
__global__ __launch_bounds__(256) void gemm32_kernel(
    const u16* __restrict__ A0, const float* __restrict__ LS,
    const u16* __restrict__ BwT, int N, int K,
    const float* __restrict__ bias,
    u16* __restrict__ outB,
    const u16* __restrict__ eA16, const u16* __restrict__ eK16,
    const float* __restrict__ eX) {
  __shared__ u16 As[32][72];
  __shared__ u16 Bs[128][72];
  int tid = threadIdx.x;
  int lane = tid & 63, w = tid >> 6, quad = lane >> 4, l16 = lane & 15;
  int n0 = blockIdx.x * 128, m0 = blockIdx.y * 32;
  int ra = tid >> 3, ca = (tid & 7) * 8;
  const size_t SP = (size_t)8192 * 384;
  floatx4 acc[2][2];
#pragma unroll
  for (int i = 0; i < 2; i++)
#pragma unroll
    for (int j = 0; j < 2; j++) acc[i][j] = zero4();

  short8 pa, pb[4];
  auto loadAB = [&](int k0) {
    if (EPI == 9) {
      const u16* p = A0 + (size_t)(m0 + ra) * 384 + k0 + ca;
      sh8u a0, a1, a2, a3, pk;
      a0.v = *(const short8*)p;
      a1.v = *(const short8*)(p + SP);
      a2.v = *(const short8*)(p + 2 * SP);
      a3.v = *(const short8*)(p + 3 * SP);
#pragma unroll
      for (int j = 0; j < 8; j++)
        pk.u[j] = f2b((b2f(a0.u[j]) + b2f(a1.u[j])) + (b2f(a2.u[j]) + b2f(a3.u[j])));
      pa = pk.v;
    } else {
      pa = *(const short8*)(A0 + (size_t)(m0 + ra) * K + k0 + ca);
    }
#pragma unroll
    for (int i = 0; i < 4; i++)
      pb[i] = *(const short8*)(BwT + (size_t)(n0 + ra + 32 * i) * K + k0 + ca);
  };
  loadAB(0);
  int iters = K >> 6;
  for (int kt = 0; kt < iters; kt++) {
    __syncthreads();
    *(short8*)&As[ra][ca] = pa;
#pragma unroll
    for (int i = 0; i < 4; i++) *(short8*)&Bs[ra + 32 * i][ca] = pb[i];
    __syncthreads();
    if (kt + 1 < iters) loadAB((kt + 1) * 64);
#pragma unroll
    for (int kh = 0; kh < 2; kh++) {
      short8 af[2], bfr[2];
#pragma unroll
      for (int mt = 0; mt < 2; mt++)
        af[mt] = *(const short8*)&As[mt * 16 + l16][kh * 32 + quad * 8];
#pragma unroll
      for (int nt = 0; nt < 2; nt++)
        bfr[nt] = *(const short8*)&Bs[w * 32 + nt * 16 + l16][kh * 32 + quad * 8];
#pragma unroll
      for (int mt = 0; mt < 2; mt++)
#pragma unroll
        for (int nt = 0; nt < 2; nt++)
          acc[mt][nt] = mfma16(af[mt], bfr[nt], acc[mt][nt]);
    }
  }

#pragma unroll
  for (int mt = 0; mt < 2; mt++) {
    int row0 = m0 + mt * 16 + quad * 4;
    float rl[4];
    if (EPI == 9) {
#pragma unroll
      for (int r = 0; r < 4; r++) {
        int gr = row0 + r;
        rl[r] = 1.f / ((LS[gr] + LS[8192 + gr]) + (LS[16384 + gr] + LS[24576 + gr]));
      }
    }
#pragma unroll
    for (int nt = 0; nt < 2; nt++) {
      int col = n0 + w * 32 + nt * 16 + l16;
#pragma unroll
      for (int r = 0; r < 4; r++) {
        size_t rc = (size_t)(row0 + r) * N + col;
        float v = acc[mt][nt][r];
        if (EPI == 9) {
          outB[rc] = f2b(v * rl[r] + bias[col]);
        } else {
          float gte = 1.f / (1.f + __expf(-(v + bias[col])));
          float fu = (1.f - gte) * b2f(eA16[rc]) + gte * b2f(eK16[rc]);
          outB[rc] = f2b(eX[rc] + fu);
        }
      }
    }
  }
}

// ------- fat kernel: attention (blocks 0..1535, 4 splits) + EdgeConv knn (1536..3583) -------
// attn: 4 waves x 32 q-rows, key-split=4, lsum via ones-MFMA, bf16 partials.
__global__ __launch_bounds__(256) void attnknn_kernel(
    const u16* __restrict__ qkv, const u16* __restrict__ Vt,
    u16* __restrict__ OPb, float* __restrict__ LS,
    const u16* __restrict__ GBb, const int* __restrict__ kidx,
    const float* __restrict__ bknn, u16* __restrict__ knn_bf) {
  __shared__ u16 Ks[64][72];    // K tile [key][dim]
  __shared__ u16 Vts[64][72];   // V^T tile [dim][key]
  __shared__ u16 Ps[4][32][72]; // per-wave P [qrow(32)][key]
  int bid = blockIdx.x, tid = threadIdx.x;
  int lane = tid & 63, w = tid >> 6, quad = lane >> 4, l16 = lane & 15;
  if (bid >= 1536) {
    // ---- EdgeConv gather + leaky-relu + max over K=8 ----
    int row = (bid - 1536) * 4 + w;  // 0..8191
    int b = row >> 11, n = row & 2047;
    float base[6], acc[6];
#pragma unroll
    for (int j = 0; j < 6; j++) {
      int d = lane + 64 * j;
      base[j] = b2f(GBb[(size_t)row * 768 + 384 + d]) + bknn[d];
      acc[j] = -1e30f;
    }
    for (int kk = 0; kk < 8; kk++) {
      int g = kidx[(b * 8 + kk) * 2048 + n];
      const u16* Gr = GBb + (size_t)g * 768;
#pragma unroll
      for (int j = 0; j < 6; j++) {
        float v = b2f(Gr[lane + 64 * j]) + base[j];
        v = v > 0.f ? v : 0.2f * v;
        acc[j] = fmaxf(acc[j], v);
      }
    }
#pragma unroll
    for (int j = 0; j < 6; j++)
      knn_bf[(size_t)row * 384 + lane + 64 * j] = f2b(acc[j]);
    return;
  }
  int split = bid / 384;
  int rr = bid - split * 384;
  int bh = rr >> 4, b = bh / 6, h = bh % 6;
  int q0 = (rr & 15) * 128;
  const u16* qbase = qkv + (size_t)b * 2048 * 1152 + h * 64;
  const u16* kbase = qbase + 384 + (size_t)split * 512 * 1152;
  const u16* vtb = Vt + (size_t)bh * 64 * 2048 + split * 512;
  short8 qf[2][2];
#pragma unroll
  for (int s = 0; s < 2; s++) {
    int qrow = q0 + w * 32 + s * 16 + l16;
    qf[s][0] = *(const short8*)(qbase + (size_t)qrow * 1152 + quad * 8);
    qf[s][1] = *(const short8*)(qbase + (size_t)qrow * 1152 + 32 + quad * 8);
  }
  short8 ones;
#pragma unroll
  for (int j = 0; j < 8; j++) ones[j] = (short)0x3F80;  // bf16 1.0
  floatx4 O[4][2];
  floatx4 accL[2] = {zero4(), zero4()};  // row-sum accumulator via ones-MFMA
#pragma unroll
  for (int i = 0; i < 4; i++)
#pragma unroll
    for (int s = 0; s < 2; s++) O[i][s] = zero4();

  int rb = tid >> 3, c8 = (tid & 7) * 8;
  short8 rk[2], rv[2];
  rk[0] = *(const short8*)(kbase + (size_t)rb * 1152 + c8);
  rk[1] = *(const short8*)(kbase + (size_t)(rb + 32) * 1152 + c8);
  rv[0] = *(const short8*)(vtb + (size_t)rb * 2048 + c8);
  rv[1] = *(const short8*)(vtb + (size_t)(rb + 32) * 2048 + c8);

  for (int kt = 0; kt < 8; kt++) {
    __syncthreads();  // previous tile's frag reads done
    *(short8*)&Ks[rb][c8] = rk[0];
    *(short8*)&Ks[rb + 32][c8] = rk[1];
    *(short8*)&Vts[rb][c8] = rv[0];
    *(short8*)&Vts[rb + 32][c8] = rv[1];
    __syncthreads();
    if (kt < 7) {
      int key0 = (kt + 1) * 64;
      rk[0] = *(const short8*)(kbase + (size_t)(key0 + rb) * 1152 + c8);
      rk[1] = *(const short8*)(kbase + (size_t)(key0 + rb + 32) * 1152 + c8);
      rv[0] = *(const short8*)(vtb + (size_t)rb * 2048 + key0 + c8);
      rv[1] = *(const short8*)(vtb + (size_t)(rb + 32) * 2048 + key0 + c8);
    }
    // S^T: st = S^T[key=mt*16+quad*4+r][q = s*16+l16]
#pragma unroll
    for (int mt = 0; mt < 4; mt++) {
      short8 k0 = *(const short8*)&Ks[mt * 16 + l16][quad * 8];
      short8 k1 = *(const short8*)&Ks[mt * 16 + l16][32 + quad * 8];
#pragma unroll
      for (int s = 0; s < 2; s++) {
        floatx4 st = mfma16(k0, qf[s][0], zero4());
        st = mfma16(k1, qf[s][1], st);
        uint2 pk;
        pk.x = permpack(exp2f(st[0]), exp2f(st[1]));
        pk.y = permpack(exp2f(st[2]), exp2f(st[3]));
        *(uint2*)&Ps[w][s * 16 + l16][mt * 16 + quad * 4] = pk;
      }
    }
    // PV + row-sum via ones-MFMA (intra-wave Ps, no barrier)
    short8 pf[2][2];
#pragma unroll
    for (int s = 0; s < 2; s++) {
      pf[s][0] = *(const short8*)&Ps[w][s * 16 + l16][quad * 8];
      pf[s][1] = *(const short8*)&Ps[w][s * 16 + l16][32 + quad * 8];
      accL[s] = mfma16(ones, pf[s][0], accL[s]);
      accL[s] = mfma16(ones, pf[s][1], accL[s]);
    }
#pragma unroll
    for (int mt2 = 0; mt2 < 4; mt2++) {
      short8 v0 = *(const short8*)&Vts[mt2 * 16 + l16][quad * 8];
      short8 v1 = *(const short8*)&Vts[mt2 * 16 + l16][32 + quad * 8];
#pragma unroll
      for (int s = 0; s < 2; s++) {
        O[mt2][s] = mfma16(v0, pf[s][0], O[mt2][s]);
        O[mt2][s] = mfma16(v1, pf[s][1], O[mt2][s]);
      }
    }
  }
  // per-split epilogue: unnormalized bf16 partials + f32 row-sum (accL rows all equal)
#pragma unroll
  for (int s = 0; s < 2; s++) {
    int row = b * 2048 + q0 + w * 32 + s * 16 + l16;
    u16* orow = OPb + (size_t)split * 8192 * 384 + (size_t)row * 384 + h * 64;
#pragma unroll
    for (int mt2 = 0; mt2 < 4; mt2++) {
      sh4u pk;
#pragma unroll
      for (int r = 0; r < 4; r++) pk.u[r] = f2b(O[mt2][s][r]);
      *(sh4v*)(orow + mt2 * 16 + quad * 4) = pk.v;
    }
    if (quad == 0) LS[split * 8192 + row] = accL[s][0];
  }
}

// ---------------- launch ----------------
extern "C" void kernel_launch(void* const* d_in, const int* in_sizes, int n_in,
                              void* d_out, int out_size, void* d_ws, size_t ws_size,
                              hipStream_t stream) {
  const float* x    = (const float*)d_in[0];
  const int* kidx   = (const int*)d_in[1];
  const float* ln1g = (const float*)d_in[2];
  const float* ln1b = (const float*)d_in[3];
  const float* wqkv = (const float*)d_in[4];
  const float* wproj= (const float*)d_in[5];
  const float* bproj= (const float*)d_in[6];
  const float* wknn = (const float*)d_in[7];
  const float* bknn = (const float*)d_in[8];
  const float* wg1  = (const float*)d_in[9];
  const float* bg1  = (const float*)d_in[10];
  const float* wg2  = (const float*)d_in[11];
  const float* bg2  = (const float*)d_in[12];
  const float* ln2g = (const float*)d_in[13];
  const float* ln2b = (const float*)d_in[14];
  const float* wfc1 = (const float*)d_in[15];
  const float* bfc1 = (const float*)d_in[16];
  const float* wfc2 = (const float*)d_in[17];
  const float* bfc2 = (const float*)d_in[18];
  float* out = (float*)d_out;

  const int M = 8192;
  char* ws = (char*)d_ws;
  size_t off = 0;
  auto alloc = [&](size_t bytes) -> char* {
    char* p = ws + off;
    off += (bytes + 255) & ~(size_t)255;
    return p;
  };
  u16* nx_bf    = (u16*)alloc((size_t)M * 384 * 2);
  u16* qkv_bf   = (u16*)alloc((size_t)M * 1152 * 2);   // + attn_bf reused as h_bf
  u16* attn_bf  = (u16*)alloc((size_t)M * 384 * 2);
  u16* GBb      = (u16*)alloc((size_t)M * 768 * 2);    // [G | base] bf16
  u16* knn_bf   = (u16*)alloc((size_t)M * 384 * 2);
  u16* x2b      = (u16*)alloc((size_t)M * 384 * 2);
  u16* t1_bf    = (u16*)alloc((size_t)M * 384 * 2);
  u16* nx2_bf   = (u16*)alloc((size_t)M * 384 * 2);
  u16* Vt_b     = (u16*)alloc((size_t)24 * 64 * 2048 * 2);
  u16* OPb      = (u16*)alloc((size_t)4 * M * 384 * 2);  // attn split partials (bf16)
  float* LS     = (float*)alloc((size_t)4 * M * 4);
  u16* wqkvT    = (u16*)alloc((size_t)1152 * 384 * 2);
  u16* wprojT   = (u16*)alloc(384 * 384 * 2);
  u16* wcT      = (u16*)alloc((size_t)768 * 384 * 2);
  u16* wg1T     = (u16*)alloc((size_t)384 * 768 * 2);
  u16* wg2T     = (u16*)alloc(384 * 384 * 2);
  u16* wfc1T    = (u16*)alloc((size_t)1536 * 384 * 2);
  u16* wfc2T    = (u16*)alloc((size_t)384 * 1536 * 2);
  u16* h_bf     = qkv_bf;  // 8192x1536 bf16 over dead qkv(18.9MB)+attn_bf(6.3MB) regions

  // weight prep + LN1 (one fat launch)
  tcln_kernel<<<2660, 256, 0, stream>>>(wqkv, wproj, wg1, wg2, wfc1, wfc2, wknn,
                                        wqkvT, wprojT, wg1T, wg2T, wfc1T, wfc2T, wcT,
                                        x, ln1g, ln1b, nx_bf);
  // fused qkv + GB: [qkv | GBb] = nx @ [wqkvT | wcT]  (960 blocks, 128-tile + prefetch)
  gemm128p_kernel<8><<<dim3(15, 64), 256, 0, stream>>>(nx_bf, wqkvT, wcT, 1920, 384,
                                                       nullptr, qkv_bf, GBb, Vt_b);
  // attention (key-split=4, ones-MFMA lsum) + knn gather-max (one fat launch)
  attnknn_kernel<<<3584, 256, 0, stream>>>(qkv_bf, Vt_b, OPb, LS,
                                           GBb, kidx, bknn, knn_bf);
  // proj: combine(OP0..OP3) @ wprojT, normalize+bias in epilogue  (768 blocks, 32-tile)
  gemm32_kernel<9><<<dim3(3, 256), 256, 0, stream>>>(OPb, LS, wprojT, 384, 384,
                                                     bproj, attn_bf,
                                                     nullptr, nullptr, nullptr);
  // gate hidden: gelu([attn|knn] @ w_g1 + b_g1) -> bf16  (384 blocks, K=768)
  gemm64_kernel<3><<<dim3(3, 128), 256, 0, stream>>>(attn_bf, knn_bf, 384, wg1T, 384, 768,
                                                     bg1, nullptr, t1_bf, nullptr);
  // gate + fuse + residual: x2b = bf16(x + (1-g)*attn + g*knn)  (768 blocks, 32-tile)
  gemm32_kernel<4><<<dim3(3, 256), 256, 0, stream>>>(t1_bf, nullptr, wg2T, 384, 384,
                                                     bg2, x2b,
                                                     attn_bf, knn_bf, x);
  // LN2 (bf16 in)
  lnb_kernel<<<2048, 256, 0, stream>>>(x2b, ln2g, ln2b, nx2_bf);
  // fc1: gelu(nx2 @ w_fc1 + b_fc1) -> bf16  (768 blocks, 128-tile + prefetch)
  gemm128p_kernel<3><<<dim3(12, 64), 256, 0, stream>>>(nx2_bf, wfc1T, nullptr, 1536, 384,
                                                       bfc1, h_bf, nullptr, nullptr);
  // fc2: out = x2 + h @ w_fc2 + b_fc2  (384 blocks, K=1536)
  gemm64_kernel<7><<<dim3(3, 128), 256, 0, stream>>>(h_bf, h_bf, 1536, wfc2T, 384, 1536,
                                                     bfc2, out, nullptr, x2b);
  (void)in_sizes; (void)n_in; (void)out_size; (void)ws_size;
}